// Round 6
// baseline (902.667 us; speedup 1.0000x reference)
//
#include <hip/hip_runtime.h>
#include <math.h>

#define HPIX 160
#define WPIX 160
#define NPIX 25600      // 160*160
#define C0   128
#define CM   64
#define MID  16
#define KK   11
#define KK2  121
#define PAD  5
#define PADW 176        // 160 + 2*5, rounded up to 16 for row alignment
#define PADH 170
#define CHP  (PADH*PADW)   // 29920 floats per padded channel
#define NBX  (NPIX/256)    // 100 pixel-blocks for conv kernels
#define BN_EPS 1e-5f

__device__ __forceinline__ float elu_f(float y) { return y > 0.f ? y : expm1f(y); }

// ---------------- act = elu(bn1(x)), vectorized float4 ----------------
__global__ __launch_bounds__(256) void k_act(
        const float* __restrict__ x,
        const float* __restrict__ g1, const float* __restrict__ b1,
        const float* __restrict__ m1, const float* __restrict__ v1,
        float* __restrict__ act) {
    int i4 = blockIdx.x * 256 + threadIdx.x;
    int c = i4 / (NPIX / 4);
    float inv  = g1[c] * rsqrtf(v1[c] + BN_EPS);
    float beta = b1[c] - m1[c] * inv;
    float4 xv = ((const float4*)x)[i4];
    float4 o;
    o.x = elu_f(fmaf(xv.x, inv, beta));
    o.y = elu_f(fmaf(xv.y, inv, beta));
    o.z = elu_f(fmaf(xv.z, inv, beta));
    o.w = elu_f(fmaf(xv.w, inv, beta));
    ((float4*)act)[i4] = o;
}

// ---------------- conv1: act -> elu(bn2(w1 @ act)) into padded feat ----
// grid (NBX, CM/16), block 256. Thread: 1 pixel, 16 output channels.
__global__ __launch_bounds__(256, 4) void k_conv1(
        const float* __restrict__ act, const float* __restrict__ w1,
        const float* __restrict__ g2, const float* __restrict__ b2,
        const float* __restrict__ m2, const float* __restrict__ v2,
        float* __restrict__ feat_pad) {
    const int tid = threadIdx.x;
    const int p   = blockIdx.x * 256 + tid;
    const int oc0 = blockIdx.y * 16;
    const float* wbase = w1 + oc0 * C0;

    float acc[16] = {0,0,0,0,0,0,0,0,0,0,0,0,0,0,0,0};
    #pragma unroll 4
    for (int k = 0; k < C0; ++k) {
        float a = act[k * NPIX + p];
        #pragma unroll
        for (int j = 0; j < 16; ++j)
            acc[j] = fmaf(wbase[j * C0 + k], a, acc[j]);
    }

    const int h = p / WPIX, w = p % WPIX;
    const int off = (h + PAD) * PADW + (w + PAD);
    #pragma unroll
    for (int j = 0; j < 16; ++j) {
        int c = oc0 + j;
        float inv = g2[c] * rsqrtf(v2[c] + BN_EPS);
        float y = acc[j] * inv + (b2[c] - m2[c] * inv);
        feat_pad[c * CHP + off] = elu_f(y);
    }
}

// ---------------- conv_t: feat_pad -> t = relu(bn(inv_w1 @ feat)) -----------
// grid (NBX, MID/4), block 256. Thread: 1 pixel, 4 output channels.
__global__ __launch_bounds__(256, 4) void k_conv_t(
        const float* __restrict__ feat_pad, const float* __restrict__ wt,
        const float* __restrict__ g, const float* __restrict__ b,
        const float* __restrict__ m, const float* __restrict__ v,
        float* __restrict__ t) {
    const int tid = threadIdx.x;
    const int p   = blockIdx.x * 256 + tid;
    const int oc0 = blockIdx.y * 4;
    const int h = p / WPIX, w = p % WPIX;
    const int off = (h + PAD) * PADW + (w + PAD);

    float acc[4] = {0,0,0,0};
    #pragma unroll 8
    for (int k = 0; k < CM; ++k) {
        float a = feat_pad[k * CHP + off];
        #pragma unroll
        for (int j = 0; j < 4; ++j)
            acc[j] = fmaf(wt[(oc0 + j) * CM + k], a, acc[j]);
    }
    #pragma unroll
    for (int j = 0; j < 4; ++j) {
        int c = oc0 + j;
        float inv = g[c] * rsqrtf(v[c] + BN_EPS);
        t[c * NPIX + p] = fmaxf(acc[j] * inv + (b[c] - m[c] * inv), 0.f);
    }
}

// ---------------- involution: wk-gen + 11x11 weighted sum + bn3 + elu -------
// Block 256, covers 16 consecutive px (one row) x 64 channels.
__global__ __launch_bounds__(256, 4) void k_involution(
        const float* __restrict__ t, const float* __restrict__ feat_pad,
        const float* __restrict__ inv_w2, const float* __restrict__ inv_b2,
        const float* __restrict__ g3, const float* __restrict__ b3,
        const float* __restrict__ m3, const float* __restrict__ v3,
        float* __restrict__ out) {
    __shared__ float s_wk[484 * 16];   // [j][px], ~31 KB
    __shared__ float s_t[MID * 16];

    // T1 XCD swizzle: gridDim.x = 1600 (divisible by 8) -> bijective
    const int q   = gridDim.x >> 3;
    const int b   = blockIdx.x;
    const int bid = (b & 7) * q + (b >> 3);

    const int tid = threadIdx.x;
    const int p0  = bid * 16;          // 16 consecutive px, same image row
    const int px  = tid & 15;
    const int c4  = tid >> 4;          // 0..15

    s_t[tid] = t[c4 * NPIX + p0 + px];
    __syncthreads();

    // ---- phase 2 (R4-proven form): wk[j][px]; j strided by 16 across c4
    {
        float tr[MID];
        #pragma unroll
        for (int mm = 0; mm < MID; ++mm) tr[mm] = s_t[mm * 16 + px];
        for (int j = c4; j < 484; j += 16) {
            const float4* wrow = (const float4*)(inv_w2 + j * MID);
            float acc = inv_b2[j];
            #pragma unroll
            for (int qq = 0; qq < 4; ++qq) {
                float4 wv = wrow[qq];
                acc = fmaf(wv.x, tr[qq*4+0], acc);
                acc = fmaf(wv.y, tr[qq*4+1], acc);
                acc = fmaf(wv.z, tr[qq*4+2], acc);
                acc = fmaf(wv.w, tr[qq*4+3], acc);
            }
            s_wk[j * 16 + px] = acc;
        }
    }
    __syncthreads();

    // ---- phase 3: thread = (tx px-quad, c). Register sliding window over kw,
    //      prefetch next kh row with a CLAMPED (always-valid) row index.
    const int tx = tid & 3;
    const int c  = tid >> 2;
    const int g  = c >> 4;
    const int h  = p0 / WPIX;
    const int wb = (p0 % WPIX) + tx * 4;
    const float* fbase = feat_pad + c * CHP + h * PADW + wb;
    const float* wkb   = s_wk + (g * KK2) * 16 + tx * 4;

    float4 wA = ((const float4*)fbase)[0];
    float4 wB = ((const float4*)fbase)[1];
    float4 wC = ((const float4*)fbase)[2];
    float4 wD = ((const float4*)fbase)[3];

    float acc0 = 0.f, acc1 = 0.f, acc2 = 0.f, acc3 = 0.f;
    #pragma unroll
    for (int kh = 0; kh < KK; ++kh) {
        const int nrow = (kh + 1 < KK) ? (kh + 1) : kh;   // clamped: no UB
        const float4* fp = (const float4*)(fbase + nrow * PADW);
        float4 nA = fp[0], nB = fp[1], nC = fp[2], nD = fp[3];

        float f[16] = {wA.x,wA.y,wA.z,wA.w, wB.x,wB.y,wB.z,wB.w,
                       wC.x,wC.y,wC.z,wC.w, wD.x,wD.y,wD.z,wD.w};
        const float* wr = wkb + kh * KK * 16;
        #pragma unroll
        for (int kw = 0; kw < KK; ++kw) {
            float4 wv = *(const float4*)(wr + kw * 16);
            acc0 = fmaf(wv.x, f[kw + 0], acc0);
            acc1 = fmaf(wv.y, f[kw + 1], acc1);
            acc2 = fmaf(wv.z, f[kw + 2], acc2);
            acc3 = fmaf(wv.w, f[kw + 3], acc3);
        }
        wA = nA; wB = nB; wC = nC; wD = nD;
    }

    float inv  = g3[c] * rsqrtf(v3[c] + BN_EPS);
    float beta = b3[c] - m3[c] * inv;
    float4 o;
    o.x = elu_f(fmaf(acc0, inv, beta));
    o.y = elu_f(fmaf(acc1, inv, beta));
    o.z = elu_f(fmaf(acc2, inv, beta));
    o.w = elu_f(fmaf(acc3, inv, beta));
    *(float4*)(out + c * NPIX + p0 + tx * 4) = o;
}

// ---------------- conv3: buf5 -> buf6 (64 -> 128) + deterministic partials --
// grid (NBX, C0/16). Thread: 1 pixel, 16 output channels.
// Pool partials written unconditionally to parts[c][bx] (no atomics, no init).
__global__ __launch_bounds__(256, 4) void k_conv3(
        const float* __restrict__ in, const float* __restrict__ w,
        float* __restrict__ out, float* __restrict__ parts) {
    const int tid = threadIdx.x;
    const int p   = blockIdx.x * 256 + tid;
    const int oc0 = blockIdx.y * 16;
    const float* wbase = w + oc0 * CM;

    float acc[16] = {0,0,0,0,0,0,0,0,0,0,0,0,0,0,0,0};
    #pragma unroll 4
    for (int k = 0; k < CM; ++k) {
        float a = in[k * NPIX + p];
        #pragma unroll
        for (int j = 0; j < 16; ++j)
            acc[j] = fmaf(wbase[j * CM + k], a, acc[j]);
    }
    #pragma unroll
    for (int j = 0; j < 16; ++j)
        out[(oc0 + j) * NPIX + p] = acc[j];

    __shared__ float s_red[16][4];
    const int lane = tid & 63, wid = tid >> 6;
    #pragma unroll
    for (int j = 0; j < 16; ++j) {
        float s = acc[j];
        #pragma unroll
        for (int off = 32; off; off >>= 1) s += __shfl_down(s, off);
        if (lane == 0) s_red[j][wid] = s;
    }
    __syncthreads();
    if (tid < 16) {
        float s = s_red[tid][0] + s_red[tid][1] + s_red[tid][2] + s_red[tid][3];
        parts[(oc0 + tid) * NBX + blockIdx.x] = s;   // deterministic write
    }
}

// ---------------- SE MLP: reduce partials -> 128->8 relu -> 8->128 sigmoid --
__global__ void k_se(const float* __restrict__ parts,
                     const float* __restrict__ w1, const float* __restrict__ b1,
                     const float* __restrict__ w2, const float* __restrict__ b2,
                     float* __restrict__ scale) {
    __shared__ float s_p[C0];
    __shared__ float s_h[8];
    int tid = threadIdx.x;
    float s = 0.f;
    for (int i = 0; i < NBX; ++i) s += parts[tid * NBX + i];  // fixed order
    s_p[tid] = s * (1.f / NPIX);
    __syncthreads();
    if (tid < 8) {
        float acc = b1[tid];
        for (int c = 0; c < C0; ++c) acc = fmaf(w1[tid * C0 + c], s_p[c], acc);
        s_h[tid] = fmaxf(acc, 0.f);
    }
    __syncthreads();
    float acc = b2[tid];
    #pragma unroll
    for (int j = 0; j < 8; ++j) acc = fmaf(w2[tid * 8 + j], s_h[j], acc);
    scale[tid] = 1.f / (1.f + expf(-acc));
}

// ---------------- Final: out = pre * scale[c] + x, float4 ----------------
__global__ __launch_bounds__(256) void k_final(
        const float* __restrict__ pre, const float* __restrict__ scale,
        const float* __restrict__ x, float* __restrict__ out) {
    int i4 = blockIdx.x * 256 + threadIdx.x;
    int c = i4 / (NPIX / 4);
    float sc = scale[c];
    float4 pv = ((const float4*)pre)[i4];
    float4 xv = ((const float4*)x)[i4];
    float4 o;
    o.x = fmaf(pv.x, sc, xv.x);
    o.y = fmaf(pv.y, sc, xv.y);
    o.z = fmaf(pv.z, sc, xv.z);
    o.w = fmaf(pv.w, sc, xv.w);
    ((float4*)out)[i4] = o;
}

extern "C" void kernel_launch(void* const* d_in, const int* in_sizes, int n_in,
                              void* d_out, int out_size, void* d_ws, size_t ws_size,
                              hipStream_t stream) {
    const float* x      = (const float*)d_in[0];
    const float* g1     = (const float*)d_in[1];
    const float* b1     = (const float*)d_in[2];
    const float* m1     = (const float*)d_in[3];
    const float* v1     = (const float*)d_in[4];
    const float* w1     = (const float*)d_in[5];
    const float* g2     = (const float*)d_in[6];
    const float* b2     = (const float*)d_in[7];
    const float* m2     = (const float*)d_in[8];
    const float* v2     = (const float*)d_in[9];
    const float* inv_w1 = (const float*)d_in[10];
    const float* ig     = (const float*)d_in[11];
    const float* ib     = (const float*)d_in[12];
    const float* im     = (const float*)d_in[13];
    const float* iv     = (const float*)d_in[14];
    const float* inv_w2 = (const float*)d_in[15];
    const float* inv_b2 = (const float*)d_in[16];
    const float* g3     = (const float*)d_in[17];
    const float* b3     = (const float*)d_in[18];
    const float* m3     = (const float*)d_in[19];
    const float* v3     = (const float*)d_in[20];
    const float* w3     = (const float*)d_in[21];
    const float* se_w1  = (const float*)d_in[22];
    const float* se_b1  = (const float*)d_in[23];
    const float* se_w2  = (const float*)d_in[24];
    const float* se_b2  = (const float*)d_in[25];
    float* out = (float*)d_out;

    float* ws       = (float*)d_ws;
    float* act      = ws;                        // 128*25600 (elu(bn1(x)))
    float* feat_pad = act + C0 * NPIX;           // 64 * 29920 (zero-padded)
    float* buf_t    = feat_pad + CM * CHP;       // 16 * 25600
    float* buf5     = act;                       // alias: act dead after conv_t
    float* buf6     = buf_t + MID * NPIX;        // 128 * 25600
    float* parts    = feat_pad;                  // alias: feat dead after invol
    float* scale    = buf6 + C0 * NPIX;          // 128

    // zero padded-feat border (every call; conv1 rewrites the interior)
    hipMemsetAsync(feat_pad, 0, (size_t)CM * CHP * sizeof(float), stream);

    // 1. act = elu(bn1(x)) once
    k_act<<<(C0 * NPIX / 4) / 256, 256, 0, stream>>>(x, g1, b1, m1, v1, act);

    // 2. conv1x1 128->64 + bn2+elu, into padded layout
    k_conv1<<<dim3(NBX, CM / 16), 256, 0, stream>>>(
        act, w1, g2, b2, m2, v2, feat_pad);

    // 3a. involution reduce: conv1x1 64->16 + bn + relu
    k_conv_t<<<dim3(NBX, MID / 4), 256, 0, stream>>>(
        feat_pad, inv_w1, ig, ib, im, iv, buf_t);

    // 3b. involution (wk-gen + weighted patch sum) + bn3 + elu
    k_involution<<<NPIX / 16, 256, 0, stream>>>(buf_t, feat_pad, inv_w2, inv_b2,
                                                g3, b3, m3, v3, buf5);

    // 4. conv1x1 64->128 + deterministic pool partials (into dead feat_pad)
    k_conv3<<<dim3(NBX, C0 / 16), 256, 0, stream>>>(buf5, w3, buf6, parts);

    // 5. SE MLP (reduces partials in fixed order)
    k_se<<<1, C0, 0, stream>>>(parts, se_w1, se_b1, se_w2, se_b2, scale);

    // 6. out = buf6 * scale + x
    k_final<<<(C0 * NPIX / 4) / 256, 256, 0, stream>>>(buf6, scale, x, out);
}

// Round 7
// 123.945 us; speedup vs baseline: 7.2828x; 7.2828x over previous
//
#include <hip/hip_runtime.h>
#include <math.h>

#define HPIX 160
#define WPIX 160
#define NPIX 25600      // 160*160
#define C0   128
#define CM   64
#define MID  16
#define KK   11
#define KK2  121
#define PAD  5
#define PADW 176        // 160 + 2*5, rounded up to 16 for row alignment
#define PADH 170
#define CHP  (PADH*PADW)   // 29920 floats per padded channel
#define NBX  (NPIX/256)    // 100 pixel-blocks for conv kernels
#define BN_EPS 1e-5f

__device__ __forceinline__ float elu_f(float y) { return y > 0.f ? y : expm1f(y); }

// ---------------- act = elu(bn1(x)), vectorized float4 ----------------
__global__ __launch_bounds__(256) void k_act(
        const float* __restrict__ x,
        const float* __restrict__ g1, const float* __restrict__ b1,
        const float* __restrict__ m1, const float* __restrict__ v1,
        float* __restrict__ act) {
    int i4 = blockIdx.x * 256 + threadIdx.x;
    int c = i4 / (NPIX / 4);
    float inv  = g1[c] * rsqrtf(v1[c] + BN_EPS);
    float beta = b1[c] - m1[c] * inv;
    float4 xv = ((const float4*)x)[i4];
    float4 o;
    o.x = elu_f(fmaf(xv.x, inv, beta));
    o.y = elu_f(fmaf(xv.y, inv, beta));
    o.z = elu_f(fmaf(xv.z, inv, beta));
    o.w = elu_f(fmaf(xv.w, inv, beta));
    ((float4*)act)[i4] = o;
}

// ---------------- conv1: act -> elu(bn2(w1 @ act)) into padded feat ----
// grid (NBX, CM/16), block 256. Thread: 1 pixel, 16 output channels.
__global__ __launch_bounds__(256, 4) void k_conv1(
        const float* __restrict__ act, const float* __restrict__ w1,
        const float* __restrict__ g2, const float* __restrict__ b2,
        const float* __restrict__ m2, const float* __restrict__ v2,
        float* __restrict__ feat_pad) {
    const int tid = threadIdx.x;
    const int p   = blockIdx.x * 256 + tid;
    const int oc0 = blockIdx.y * 16;
    const float* wbase = w1 + oc0 * C0;

    float acc[16] = {0,0,0,0,0,0,0,0,0,0,0,0,0,0,0,0};
    #pragma unroll 4
    for (int k = 0; k < C0; ++k) {
        float a = act[k * NPIX + p];
        #pragma unroll
        for (int j = 0; j < 16; ++j)
            acc[j] = fmaf(wbase[j * C0 + k], a, acc[j]);
    }

    const int h = p / WPIX, w = p % WPIX;
    const int off = (h + PAD) * PADW + (w + PAD);
    #pragma unroll
    for (int j = 0; j < 16; ++j) {
        int c = oc0 + j;
        float inv = g2[c] * rsqrtf(v2[c] + BN_EPS);
        float y = acc[j] * inv + (b2[c] - m2[c] * inv);
        feat_pad[c * CHP + off] = elu_f(y);
    }
}

// ---------------- conv_t: feat_pad -> t = relu(bn(inv_w1 @ feat)) -----------
// grid (NBX, MID/4), block 256. Thread: 1 pixel, 4 output channels.
__global__ __launch_bounds__(256, 4) void k_conv_t(
        const float* __restrict__ feat_pad, const float* __restrict__ wt,
        const float* __restrict__ g, const float* __restrict__ b,
        const float* __restrict__ m, const float* __restrict__ v,
        float* __restrict__ t) {
    const int tid = threadIdx.x;
    const int p   = blockIdx.x * 256 + tid;
    const int oc0 = blockIdx.y * 4;
    const int h = p / WPIX, w = p % WPIX;
    const int off = (h + PAD) * PADW + (w + PAD);

    float acc[4] = {0,0,0,0};
    #pragma unroll 8
    for (int k = 0; k < CM; ++k) {
        float a = feat_pad[k * CHP + off];
        #pragma unroll
        for (int j = 0; j < 4; ++j)
            acc[j] = fmaf(wt[(oc0 + j) * CM + k], a, acc[j]);
    }
    #pragma unroll
    for (int j = 0; j < 4; ++j) {
        int c = oc0 + j;
        float inv = g[c] * rsqrtf(v[c] + BN_EPS);
        t[c * NPIX + p] = fmaxf(acc[j] * inv + (b[c] - m[c] * inv), 0.f);
    }
}

// ---------------- involution: wk-gen + 11x11 weighted sum + bn3 + elu -------
// Block 256, covers 16 consecutive px (one row) x 64 channels.
// Phase 3 uses the R4-PROVEN form: unroll 2, no prefetch (full unroll +
// prefetch spilled to scratch: 885 MB writes, 15x slowdown in R6).
__global__ __launch_bounds__(256, 4) void k_involution(
        const float* __restrict__ t, const float* __restrict__ feat_pad,
        const float* __restrict__ inv_w2, const float* __restrict__ inv_b2,
        const float* __restrict__ g3, const float* __restrict__ b3,
        const float* __restrict__ m3, const float* __restrict__ v3,
        float* __restrict__ out) {
    __shared__ float s_wk[484 * 16];   // [j][px], ~31 KB
    __shared__ float s_t[MID * 16];

    // T1 XCD swizzle: gridDim.x = 1600 (divisible by 8) -> bijective.
    // XCD k gets 200 consecutive strips = a contiguous 20-row image band;
    // band + 5-row halo of feat (~1.4 MB) fits the XCD's 4 MB L2.
    const int q   = gridDim.x >> 3;
    const int b   = blockIdx.x;
    const int bid = (b & 7) * q + (b >> 3);

    const int tid = threadIdx.x;
    const int p0  = bid * 16;          // 16 consecutive px, same image row
    const int px  = tid & 15;
    const int c4  = tid >> 4;          // 0..15

    s_t[tid] = t[c4 * NPIX + p0 + px];
    __syncthreads();

    // ---- phase 2: wk[j][px]; j strided by 16 across c4
    {
        float tr[MID];
        #pragma unroll
        for (int mm = 0; mm < MID; ++mm) tr[mm] = s_t[mm * 16 + px];
        for (int j = c4; j < 484; j += 16) {
            const float4* wrow = (const float4*)(inv_w2 + j * MID);
            float acc = inv_b2[j];
            #pragma unroll
            for (int qq = 0; qq < 4; ++qq) {
                float4 wv = wrow[qq];
                acc = fmaf(wv.x, tr[qq*4+0], acc);
                acc = fmaf(wv.y, tr[qq*4+1], acc);
                acc = fmaf(wv.z, tr[qq*4+2], acc);
                acc = fmaf(wv.w, tr[qq*4+3], acc);
            }
            s_wk[j * 16 + px] = acc;
        }
    }
    __syncthreads();

    // ---- phase 3 (R4 form): thread = (tx px-quad, c), sliding 16-float
    //      window per (c,kh), kw fully unrolled, kh unroll 2.
    const int tx = tid & 3;
    const int c  = tid >> 2;
    const int g  = c >> 4;
    const int h  = p0 / WPIX;
    const int wb = (p0 % WPIX) + tx * 4;
    const float* fbase = feat_pad + c * CHP + h * PADW + wb;
    const float* wkb   = s_wk + (g * KK2) * 16 + tx * 4;

    float acc0 = 0.f, acc1 = 0.f, acc2 = 0.f, acc3 = 0.f;
    #pragma unroll 2
    for (int kh = 0; kh < KK; ++kh) {
        const float4* fp = (const float4*)(fbase + kh * PADW);
        float4 A = fp[0], B = fp[1], Cq = fp[2], D = fp[3];
        float f[16] = {A.x,A.y,A.z,A.w, B.x,B.y,B.z,B.w,
                       Cq.x,Cq.y,Cq.z,Cq.w, D.x,D.y,D.z,D.w};
        const float* wr = wkb + kh * KK * 16;
        #pragma unroll
        for (int kw = 0; kw < KK; ++kw) {
            float4 wv = *(const float4*)(wr + kw * 16);
            acc0 = fmaf(wv.x, f[kw + 0], acc0);
            acc1 = fmaf(wv.y, f[kw + 1], acc1);
            acc2 = fmaf(wv.z, f[kw + 2], acc2);
            acc3 = fmaf(wv.w, f[kw + 3], acc3);
        }
    }

    float inv  = g3[c] * rsqrtf(v3[c] + BN_EPS);
    float beta = b3[c] - m3[c] * inv;
    float4 o;
    o.x = elu_f(fmaf(acc0, inv, beta));
    o.y = elu_f(fmaf(acc1, inv, beta));
    o.z = elu_f(fmaf(acc2, inv, beta));
    o.w = elu_f(fmaf(acc3, inv, beta));
    *(float4*)(out + c * NPIX + p0 + tx * 4) = o;
}

// ---------------- conv3: buf5 -> buf6 (64 -> 128) + deterministic partials --
// grid (NBX, C0/16). Thread: 1 pixel, 16 output channels.
__global__ __launch_bounds__(256, 4) void k_conv3(
        const float* __restrict__ in, const float* __restrict__ w,
        float* __restrict__ out, float* __restrict__ parts) {
    const int tid = threadIdx.x;
    const int p   = blockIdx.x * 256 + tid;
    const int oc0 = blockIdx.y * 16;
    const float* wbase = w + oc0 * CM;

    float acc[16] = {0,0,0,0,0,0,0,0,0,0,0,0,0,0,0,0};
    #pragma unroll 4
    for (int k = 0; k < CM; ++k) {
        float a = in[k * NPIX + p];
        #pragma unroll
        for (int j = 0; j < 16; ++j)
            acc[j] = fmaf(wbase[j * CM + k], a, acc[j]);
    }
    #pragma unroll
    for (int j = 0; j < 16; ++j)
        out[(oc0 + j) * NPIX + p] = acc[j];

    __shared__ float s_red[16][4];
    const int lane = tid & 63, wid = tid >> 6;
    #pragma unroll
    for (int j = 0; j < 16; ++j) {
        float s = acc[j];
        #pragma unroll
        for (int off = 32; off; off >>= 1) s += __shfl_down(s, off);
        if (lane == 0) s_red[j][wid] = s;
    }
    __syncthreads();
    if (tid < 16) {
        float s = s_red[tid][0] + s_red[tid][1] + s_red[tid][2] + s_red[tid][3];
        parts[(oc0 + tid) * NBX + blockIdx.x] = s;   // deterministic write
    }
}

// ---------------- SE MLP: reduce partials -> 128->8 relu -> 8->128 sigmoid --
__global__ void k_se(const float* __restrict__ parts,
                     const float* __restrict__ w1, const float* __restrict__ b1,
                     const float* __restrict__ w2, const float* __restrict__ b2,
                     float* __restrict__ scale) {
    __shared__ float s_p[C0];
    __shared__ float s_h[8];
    int tid = threadIdx.x;
    float s = 0.f;
    for (int i = 0; i < NBX; ++i) s += parts[tid * NBX + i];  // fixed order
    s_p[tid] = s * (1.f / NPIX);
    __syncthreads();
    if (tid < 8) {
        float acc = b1[tid];
        for (int c = 0; c < C0; ++c) acc = fmaf(w1[tid * C0 + c], s_p[c], acc);
        s_h[tid] = fmaxf(acc, 0.f);
    }
    __syncthreads();
    float acc = b2[tid];
    #pragma unroll
    for (int j = 0; j < 8; ++j) acc = fmaf(w2[tid * 8 + j], s_h[j], acc);
    scale[tid] = 1.f / (1.f + expf(-acc));
}

// ---------------- Final: out = pre * scale[c] + x, float4 ----------------
__global__ __launch_bounds__(256) void k_final(
        const float* __restrict__ pre, const float* __restrict__ scale,
        const float* __restrict__ x, float* __restrict__ out) {
    int i4 = blockIdx.x * 256 + threadIdx.x;
    int c = i4 / (NPIX / 4);
    float sc = scale[c];
    float4 pv = ((const float4*)pre)[i4];
    float4 xv = ((const float4*)x)[i4];
    float4 o;
    o.x = fmaf(pv.x, sc, xv.x);
    o.y = fmaf(pv.y, sc, xv.y);
    o.z = fmaf(pv.z, sc, xv.z);
    o.w = fmaf(pv.w, sc, xv.w);
    ((float4*)out)[i4] = o;
}

extern "C" void kernel_launch(void* const* d_in, const int* in_sizes, int n_in,
                              void* d_out, int out_size, void* d_ws, size_t ws_size,
                              hipStream_t stream) {
    const float* x      = (const float*)d_in[0];
    const float* g1     = (const float*)d_in[1];
    const float* b1     = (const float*)d_in[2];
    const float* m1     = (const float*)d_in[3];
    const float* v1     = (const float*)d_in[4];
    const float* w1     = (const float*)d_in[5];
    const float* g2     = (const float*)d_in[6];
    const float* b2     = (const float*)d_in[7];
    const float* m2     = (const float*)d_in[8];
    const float* v2     = (const float*)d_in[9];
    const float* inv_w1 = (const float*)d_in[10];
    const float* ig     = (const float*)d_in[11];
    const float* ib     = (const float*)d_in[12];
    const float* im     = (const float*)d_in[13];
    const float* iv     = (const float*)d_in[14];
    const float* inv_w2 = (const float*)d_in[15];
    const float* inv_b2 = (const float*)d_in[16];
    const float* g3     = (const float*)d_in[17];
    const float* b3     = (const float*)d_in[18];
    const float* m3     = (const float*)d_in[19];
    const float* v3     = (const float*)d_in[20];
    const float* w3     = (const float*)d_in[21];
    const float* se_w1  = (const float*)d_in[22];
    const float* se_b1  = (const float*)d_in[23];
    const float* se_w2  = (const float*)d_in[24];
    const float* se_b2  = (const float*)d_in[25];
    float* out = (float*)d_out;

    float* ws       = (float*)d_ws;
    float* act      = ws;                        // 128*25600 (elu(bn1(x)))
    float* feat_pad = act + C0 * NPIX;           // 64 * 29920 (zero-padded)
    float* buf_t    = feat_pad + CM * CHP;       // 16 * 25600
    float* buf5     = act;                       // alias: act dead after conv1
    float* buf6     = buf_t + MID * NPIX;        // 128 * 25600
    float* parts    = feat_pad;                  // alias: feat dead after invol
    float* scale    = buf6 + C0 * NPIX;          // 128

    // zero padded-feat border (every call; conv1 rewrites the interior)
    hipMemsetAsync(feat_pad, 0, (size_t)CM * CHP * sizeof(float), stream);

    // 1. act = elu(bn1(x)) once
    k_act<<<(C0 * NPIX / 4) / 256, 256, 0, stream>>>(x, g1, b1, m1, v1, act);

    // 2. conv1x1 128->64 + bn2+elu, into padded layout
    k_conv1<<<dim3(NBX, CM / 16), 256, 0, stream>>>(
        act, w1, g2, b2, m2, v2, feat_pad);

    // 3a. involution reduce: conv1x1 64->16 + bn + relu
    k_conv_t<<<dim3(NBX, MID / 4), 256, 0, stream>>>(
        feat_pad, inv_w1, ig, ib, im, iv, buf_t);

    // 3b. involution (wk-gen + weighted patch sum) + bn3 + elu
    k_involution<<<NPIX / 16, 256, 0, stream>>>(buf_t, feat_pad, inv_w2, inv_b2,
                                                g3, b3, m3, v3, buf5);

    // 4. conv1x1 64->128 + deterministic pool partials (into dead feat_pad)
    k_conv3<<<dim3(NBX, C0 / 16), 256, 0, stream>>>(buf5, w3, buf6, parts);

    // 5. SE MLP (reduces partials in fixed order)
    k_se<<<1, C0, 0, stream>>>(parts, se_w1, se_b1, se_w2, se_b2, scale);

    // 6. out = buf6 * scale + x
    k_final<<<(C0 * NPIX / 4) / 256, 256, 0, stream>>>(buf6, scale, x, out);
}